// Round 9
// baseline (143.899 us; speedup 1.0000x reference)
//
#include <hip/hip_runtime.h>

typedef unsigned short u16;
typedef unsigned int u32;
typedef unsigned long long u64;
typedef __bf16 bf16x8 __attribute__((ext_vector_type(8)));
typedef __bf16 bf16x4 __attribute__((ext_vector_type(4)));
typedef u16 u16x8 __attribute__((ext_vector_type(8)));
typedef float f32x4 __attribute__((ext_vector_type(4)));
typedef float f32x16 __attribute__((ext_vector_type(16)));
typedef u32 u32x4 __attribute__((ext_vector_type(4)));

// ---------------- helpers ----------------
__device__ __forceinline__ u16 f2bf(float f) {
    return __builtin_bit_cast(u16, (__bf16)f);   // RNE
}
__device__ __forceinline__ float bf2f(u16 v) {
    u32 u = ((u32)v) << 16;
    return __builtin_bit_cast(float, u);
}

__device__ __forceinline__ void gl_lds16(const void* g, void* l) {
    __builtin_amdgcn_global_load_lds(
        (const __attribute__((address_space(1))) unsigned int*)g,
        (__attribute__((address_space(3))) unsigned int*)l, 16, 0, 0);
}

// log2(e)/8 folded into Q projection; fixed softmax origin m=16 (|s|<~6).
#define QSCALE 0.18033688011112042f

// ---------------- mask dtype sniff + LUT build ----------------
// lut[16][4]: entry n, elem r = (n>>r)&1 ? -16 : -1e5  (MFMA C-in = origin + mask)
__global__ void detect_mask(const unsigned char* __restrict__ m, int* __restrict__ flag,
                            float* __restrict__ lut) {
    int t = threadIdx.x;
    lut[t] = (((t >> 2) >> (t & 3)) & 1) ? -16.0f : -100000.0f;
    if (t == 0) {
        int any0 = 0, any1 = 0;
        for (int g = 0; g < 64; ++g) {
            any0 |= (m[4 * g] != 0);
            any1 |= (m[4 * g + 1] != 0);
        }
        *flag = any1 ? 0 : (any0 ? 1 : 2);
    }
}

// ---------------- fused prep: bf16 convert | weight transposes | rope | mask pack ----
__global__ void prep(const float4* __restrict__ inq, const float4* __restrict__ inkv,
                     ushort4* __restrict__ oAq, ushort4* __restrict__ oAkv,
                     const float* __restrict__ Wq, const float* __restrict__ Wk,
                     const float* __restrict__ Wv, const float* __restrict__ Wo,
                     u16* __restrict__ Wcat, u16* __restrict__ Wot,
                     const void* __restrict__ mask, const int* __restrict__ flagp,
                     u64* __restrict__ Mb, float2* __restrict__ rtbl) {
    int bid = blockIdx.x;
    const int tid = threadIdx.x;
    if (bid < 8192) {
        int i = bid * 256 + tid;
        const float4* src; ushort4* dst; int j;
        if (i < 1048576) { src = inq;  dst = oAq;  j = i; }
        else             { src = inkv; dst = oAkv; j = i - 1048576; }
        float4 f = src[j];
        ushort4 o;
        o.x = f2bf(f.x); o.y = f2bf(f.y); o.z = f2bf(f.z); o.w = f2bf(f.w);
        dst[j] = o;
        return;
    }
    bid -= 8192;
    if (bid < 2176) {
        const float* src; u16* dst; int C, bx, by;
        if (bid < 1024)      { src = Wq; dst = Wcat;           C = 1024; bx = bid & 31;          by = bid >> 5; }
        else if (bid < 2048) { src = Wo; dst = Wot;            C = 1024; bx = (bid - 1024) & 31; by = (bid - 1024) >> 5; }
        else if (bid < 2112) { src = Wk; dst = Wcat + 1048576; C = 64;   bx = (bid - 2048) & 1;  by = (bid - 2048) >> 1; }
        else                 { src = Wv; dst = Wcat + 1114112; C = 64;   bx = (bid - 2112) & 1;  by = (bid - 2112) >> 1; }
        __shared__ float t[32][33];
        int tx = tid & 31, ty = tid >> 5;
        bx *= 32; by *= 32;
#pragma unroll
        for (int i = 0; i < 4; ++i)
            t[ty + i * 8][tx] = src[(size_t)(by + ty + i * 8) * C + bx + tx];
        __syncthreads();
#pragma unroll
        for (int i = 0; i < 4; ++i)
            dst[(size_t)(bx + ty + i * 8) * 1024 + by + tx] = f2bf(t[tx][ty + i * 8]);
        return;
    }
    bid -= 2176;
    if (bid < 256) {
        int i = bid * 256 + tid;
        int pos = i >> 5, j = i & 31;
        float inv = powf(10000.0f, -(float)(2 * j) * (1.0f / 64.0f));
        float s, c;
        sincosf((float)pos * inv, &s, &c);
        rtbl[i] = make_float2(c, s);
        return;
    }
    bid -= 256;
    {
        int flag = *flagp;
        int lane = tid & 63;
        for (int wid = bid * 4 + (tid >> 6); wid < 131072; wid += 8192) {
            size_t idx = (size_t)wid * 64 + lane;
            bool v;
            if (flag == 0)      v = ((const unsigned char*)mask)[idx] != 0;
            else if (flag == 1) v = ((const int*)mask)[idx] != 0;
            else                v = ((const float*)mask)[idx] != 0.f;
            u64 bm = __ballot(v);
            if (lane == 0) Mb[wid] = bm;
        }
    }
}

// ---------------- GEMM: C(M=4096, Ntiles*128) = A(M,1024) @ Bt(N,1024)^T -------------
// 64Mx128N, 4 waves. Staging via global_load_lds (pre-swizzled global src, linear LDS
// dest, swizzled reads — rule #21), double-buffered, one barrier per K-step.
// MODE 0: fused QKV projection (K/V outputs in 8B-XOR-swizzled layouts for flash).
// MODE 2: output projection (+bo), f32 store.
template <int MODE>
__launch_bounds__(256)
__global__ void gemm_bt(const u16* __restrict__ A0, const u16* __restrict__ A1,
                        const u16* __restrict__ Bt,
                        const float* __restrict__ b1, const float* __restrict__ b2,
                        const float* __restrict__ b3,
                        const float2* __restrict__ rtbl,
                        u16* __restrict__ oQ, u16* __restrict__ oK, u16* __restrict__ oV,
                        float* __restrict__ oF, int Ntiles) {
    __shared__ __align__(16) u16 lA[2][64 * 64];
    __shared__ __align__(16) u16 lB[2][128 * 64];
    const int tid = threadIdx.x, w = tid >> 6, lane = tid & 63;
    const int tm = blockIdx.x / Ntiles, tn = blockIdx.x % Ntiles;
    const int wm = w >> 1, wn = w & 1;
    const int lq = lane & 15, g = lane >> 4, g4 = g << 2;
    const u32 swz = (lane & 7) << 4;
    const u32 bcolg = (16 * g) ^ swz;
    const u16* A = (MODE == 0 && tn == 8) ? A1 : A0;

    // staging: thread -> (row rs, 8-elem chunk ch), global col pre-XOR-swizzled
    const int rs = tid >> 3, ch = tid & 7;
    const u32 sc = (u32)((ch ^ (rs & 7)) * 8);   // swizzled elem offset within 64-col row
    const u16* gA0 = A + (size_t)(tm * 64 + rs) * 1024 + sc;
    const u16* gA1 = gA0 + 32 * 1024;
    const u16* gB0 = Bt + (size_t)(tn * 128 + rs) * 1024 + sc;
    const u16* gB1 = gB0 + 32 * 1024;
    const u16* gB2 = gB0 + 64 * 1024;
    const u16* gB3 = gB0 + 96 * 1024;

#define GSTAGE(BUFI, T)                                                        \
    {                                                                          \
        gl_lds16(gA0 + (T) * 64, (char*)lA + (BUFI) * 8192 + tid * 16);        \
        gl_lds16(gA1 + (T) * 64, (char*)lA + (BUFI) * 8192 + 4096 + tid * 16); \
        gl_lds16(gB0 + (T) * 64, (char*)lB + (BUFI) * 16384 + tid * 16);       \
        gl_lds16(gB1 + (T) * 64, (char*)lB + (BUFI) * 16384 + 4096 + tid * 16);\
        gl_lds16(gB2 + (T) * 64, (char*)lB + (BUFI) * 16384 + 8192 + tid * 16);\
        gl_lds16(gB3 + (T) * 64, (char*)lB + (BUFI) * 16384 + 12288 + tid * 16);\
    }

    f32x4 acc[2][4] = {};

    GSTAGE(0, 0);
    __syncthreads();

#pragma unroll
    for (int t = 0; t < 16; ++t) {
        if (t < 15) GSTAGE((t + 1) & 1, t + 1);
        const char* bA = (const char*)lA + (t & 1) * 8192;
        const char* bB = (const char*)lB + (t & 1) * 16384;
#pragma unroll
        for (int kc = 0; kc < 2; ++kc) {
            const u32 col = bcolg ^ (64 * kc);
            bf16x8 af0 = *(const bf16x8*)(bA + (wm * 32 + lq) * 128 + col);
            bf16x8 af1 = *(const bf16x8*)(bA + (wm * 32 + 16 + lq) * 128 + col);
            bf16x8 bg0 = *(const bf16x8*)(bB + (wn * 64 + lq) * 128 + col);
            bf16x8 bg1 = *(const bf16x8*)(bB + (wn * 64 + 16 + lq) * 128 + col);
            bf16x8 bg2 = *(const bf16x8*)(bB + (wn * 64 + 32 + lq) * 128 + col);
            bf16x8 bg3 = *(const bf16x8*)(bB + (wn * 64 + 48 + lq) * 128 + col);
            acc[0][0] = __builtin_amdgcn_mfma_f32_16x16x32_bf16(af0, bg0, acc[0][0], 0, 0, 0);
            acc[0][1] = __builtin_amdgcn_mfma_f32_16x16x32_bf16(af0, bg1, acc[0][1], 0, 0, 0);
            acc[0][2] = __builtin_amdgcn_mfma_f32_16x16x32_bf16(af0, bg2, acc[0][2], 0, 0, 0);
            acc[0][3] = __builtin_amdgcn_mfma_f32_16x16x32_bf16(af0, bg3, acc[0][3], 0, 0, 0);
            acc[1][0] = __builtin_amdgcn_mfma_f32_16x16x32_bf16(af1, bg0, acc[1][0], 0, 0, 0);
            acc[1][1] = __builtin_amdgcn_mfma_f32_16x16x32_bf16(af1, bg1, acc[1][1], 0, 0, 0);
            acc[1][2] = __builtin_amdgcn_mfma_f32_16x16x32_bf16(af1, bg2, acc[1][2], 0, 0, 0);
            acc[1][3] = __builtin_amdgcn_mfma_f32_16x16x32_bf16(af1, bg3, acc[1][3], 0, 0, 0);
        }
        __syncthreads();
    }
#undef GSTAGE

    // epilogue
#pragma unroll
    for (int mi = 0; mi < 2; ++mi) {
#pragma unroll
        for (int ni = 0; ni < 4; ++ni) {
#pragma unroll
            for (int r = 0; r < 4; ++r) {
                int grow = tm * 64 + wm * 32 + mi * 16 + g4 + r;
                float v = acc[mi][ni][r];
                if constexpr (MODE == 0) {
                    int pos = grow & 2047;
                    if (tn < 8) {
                        int gcol = tn * 128 + wn * 64 + ni * 16 + lq;
                        v += b1[gcol];
                        float2 cs = rtbl[pos * 32 + ((gcol & 63) >> 1)];
                        float prt = __shfl_xor(v, 1);
                        v = (gcol & 1) ? (v * cs.x + prt * cs.y) : (v * cs.x - prt * cs.y);
                        v *= QSCALE;
                        oQ[(size_t)grow * 1024 + gcol] = f2bf(v);
                    } else {
                        int lc = wn * 64 + ni * 16 + lq;
                        if (lc < 64) {   // K: 8B-block XOR swizzle within 128B row
                            v += b2[lc];
                            float2 cs = rtbl[pos * 32 + (lc >> 1)];
                            float prt = __shfl_xor(v, 1);
                            v = (lc & 1) ? (v * cs.x + prt * cs.y) : (v * cs.x - prt * cs.y);
                            oK[(size_t)grow * 64 + ((((u32)lc >> 2) ^ ((u32)grow & 15)) << 2)
                               + (lc & 3)] = f2bf(v);
                        } else {         // V^T [b][d][kk], swizzled within each 64-kk chunk
                            int d = lc - 64;
                            v += b3[d];
                            int b = grow >> 11, ll = grow & 2047;
                            int cc = ll & 63;
                            oV[((size_t)(b * 64 + d)) * 2048 + (ll & ~63)
                               + ((((u32)cc >> 2) ^ ((u32)d & 15)) << 2) + (cc & 3)] = f2bf(v);
                        }
                    }
                } else {
                    int gcol = tn * 128 + wn * 64 + ni * 16 + lq;
                    oF[(size_t)grow * 1024 + gcol] = v + b1[gcol];
                }
            }
        }
    }
}

// ---------------- flash attention: 32x32 MFMA, in-reg P, 2-way split-KV -------------
// grid: b*512 + hh*32 + qt*2 + s. 4 waves x 32 q. Each block: 16 KV chunks (1024 kv).
// Fixed-origin softmax => partials combine linearly: o=oA+oB, l=lA+lB (combine kernel).
// Register plan for __launch_bounds__(256,4) (total budget 128, unified VGPR+AGPR):
//   o-acc 32 + qf 16 + dof 8 + ptrs/mask ~14 + transient (st 16, pa 8, vv/kf 4, cvt 4)
//   ≈ 110-120. Achieved by consuming each pa pair in PV immediately after its QKHALF
//   (QK1 -> PV1 -> QK2 -> PV2), so only 2 pa fragments are ever live.
//   GUARD: if WRITE_SIZE balloons past ~50 MB, this spilled — revert to (256,3).
#define MFMA32(A, B, C) __builtin_amdgcn_mfma_f32_32x32x16_bf16(A, B, C, 0, 0, 0)

__launch_bounds__(256, 4)
__global__ void flash(const u16* __restrict__ Qb, const u16* __restrict__ Kb,
                      const u16* __restrict__ Vt, const u64* __restrict__ Mb,
                      const f32x4* __restrict__ lut,
                      u16* __restrict__ oPa, u16* __restrict__ oPb,
                      float* __restrict__ lsPa, float* __restrict__ lsPb) {
    __shared__ __align__(16) u16 lK[2][64 * 64];   // [kk][d], 8B-XOR swizzled
    __shared__ __align__(16) u16 lV[2][64 * 64];   // [d][kk], 8B-XOR swizzled
    __shared__ f32x4 slut[16];
    const int tid = threadIdx.x, w = tid >> 6, lane = tid & 63;
    const int s = blockIdx.x & 1, qt = (blockIdx.x >> 1) & 15;
    const int hh = (blockIdx.x >> 5) & 15, b = blockIdx.x >> 9;
    const int qb = qt * 128 + w * 32;
    const int l31 = lane & 31, h = lane >> 5, l15 = lane & 15;

    if (tid < 16) slut[tid] = lut[tid];

    // Q fragments (B-operand): lane holds Q[qb+l31][dsub*16 + h*8 + j]
    bf16x8 qf0, qf1, qf2, qf3;
    {
        const u16* qp = Qb + (size_t)(b * 2048 + qb + l31) * 1024 + hh * 64 + h * 8;
        qf0 = *(const bf16x8*)(qp);
        qf1 = *(const bf16x8*)(qp + 16);
        qf2 = *(const bf16x8*)(qp + 32);
        qf3 = *(const bf16x8*)(qp + 48);
    }

    const u64* mp = Mb + (size_t)(b * 2048 + qb + l31) * 32 + s * 16;

    // swizzled 8B-slot offsets: dof[j] for slot j = (j>>1)*4 + 2h + (j&1)
    u32 dof0 = ((u32)(2 * h) ^ l15) << 3,      dof1 = ((u32)(2 * h + 1) ^ l15) << 3;
    u32 dof2 = ((u32)(4 + 2 * h) ^ l15) << 3,  dof3 = ((u32)(5 + 2 * h) ^ l15) << 3;
    u32 dof4 = ((u32)(8 + 2 * h) ^ l15) << 3,  dof5 = ((u32)(9 + 2 * h) ^ l15) << 3;
    u32 dof6 = ((u32)(12 + 2 * h) ^ l15) << 3, dof7 = ((u32)(13 + 2 * h) ^ l15) << 3;
    const char* kvbase = (const char*)lK + l31 * 128;

    // staging pointers (linear; global layouts pre-swizzled); start at this half's KV
    const u16* pK = Kb + (size_t)b * 131072 + (size_t)s * 65536 + tid * 8;
    const u16* pV = Vt + (size_t)(b * 64 + (tid >> 3)) * 2048 + s * 1024 + (tid & 7) * 8;
    const u16* pV2 = pV + 32 * 2048;

#define STAGE(BUF)                                                       \
    {                                                                    \
        gl_lds16(pK,        (char*)lK + (BUF) * 8192 + tid * 16);        \
        gl_lds16(pK + 2048, (char*)lK + (BUF) * 8192 + 4096 + tid * 16); \
        gl_lds16(pV,        (char*)lV + (BUF) * 8192 + tid * 16);        \
        gl_lds16(pV2,       (char*)lV + (BUF) * 8192 + 4096 + tid * 16); \
        pK += 4096; pV += 64; pV2 += 64;                                 \
    }

    f32x16 o0 = {}, o1 = {};
    float lsum = 0.f;
    u64 mwc;

#define FRAG(DST, IMM, OFA, OFB)                                             \
    {                                                                        \
        bf16x4 lo_ = *(const bf16x4*)(kvbase + (IMM) + (OFA));               \
        bf16x4 hi_ = *(const bf16x4*)(kvbase + (IMM) + (OFB));               \
        DST = __builtin_shufflevector(lo_, hi_, 0, 1, 2, 3, 4, 5, 6, 7);     \
    }

#define MKPA(PA, E0, E1, E2, E3, E4, E5, E6, E7)                             \
    {                                                                        \
        u32 x0_, x1_, y0_, y1_;                                              \
        asm("v_cvt_pk_bf16_f32 %0, %1, %2" : "=v"(x0_) : "v"(E0), "v"(E1));  \
        asm("v_cvt_pk_bf16_f32 %0, %1, %2" : "=v"(x1_) : "v"(E2), "v"(E3));  \
        asm("v_cvt_pk_bf16_f32 %0, %1, %2" : "=v"(y0_) : "v"(E4), "v"(E5));  \
        asm("v_cvt_pk_bf16_f32 %0, %1, %2" : "=v"(y1_) : "v"(E6), "v"(E7));  \
        asm("v_permlane32_swap_b32 %0, %1" : "+v"(x0_), "+v"(y0_));          \
        asm("v_permlane32_swap_b32 %0, %1" : "+v"(x1_), "+v"(y1_));          \
        u32x4 t_ = {x0_, x1_, y0_, y1_};                                     \
        PA = __builtin_bit_cast(bf16x8, t_);                                 \
    }

// one S^T half: C-in from LUT, 4 QK MFMAs, exp2, lsum, pack -> PA0/PA1. st dies here.
#define QKHALF(KIMM, MS, PA0, PA1)                                                      \
    {                                                                                   \
        f32x16 st;                                                                      \
        {                                                                               \
            f32x4 c0_ = slut[(u32)(MS) & 15];                                           \
            f32x4 c1_ = slut[(u32)((MS) >> 8) & 15];                                    \
            f32x4 c2_ = slut[(u32)((MS) >> 16) & 15];                                   \
            f32x4 c3_ = slut[(u32)((MS) >> 24) & 15];                                   \
            st[0] = c0_[0]; st[1] = c0_[1]; st[2] = c0_[2]; st[3] = c0_[3];             \
            st[4] = c1_[0]; st[5] = c1_[1]; st[6] = c1_[2]; st[7] = c1_[3];             \
            st[8] = c2_[0]; st[9] = c2_[1]; st[10] = c2_[2]; st[11] = c2_[3];           \
            st[12] = c3_[0]; st[13] = c3_[1]; st[14] = c3_[2]; st[15] = c3_[3];         \
        }                                                                               \
        __builtin_amdgcn_s_setprio(1);                                                  \
        {                                                                               \
            bf16x8 kf;                                                                  \
            FRAG(kf, (KIMM), dof0, dof1); st = MFMA32(kf, qf0, st);                     \
            FRAG(kf, (KIMM), dof2, dof3); st = MFMA32(kf, qf1, st);                     \
            FRAG(kf, (KIMM), dof4, dof5); st = MFMA32(kf, qf2, st);                     \
            FRAG(kf, (KIMM), dof6, dof7); st = MFMA32(kf, qf3, st);                     \
        }                                                                               \
        __builtin_amdgcn_s_setprio(0);                                                  \
        float e0 = exp2f(st[0]), e1 = exp2f(st[1]), e2 = exp2f(st[2]),                  \
              e3 = exp2f(st[3]), e4 = exp2f(st[4]), e5 = exp2f(st[5]),                  \
              e6 = exp2f(st[6]), e7 = exp2f(st[7]), e8 = exp2f(st[8]),                  \
              e9 = exp2f(st[9]), e10 = exp2f(st[10]), e11 = exp2f(st[11]),              \
              e12 = exp2f(st[12]), e13 = exp2f(st[13]), e14 = exp2f(st[14]),            \
              e15 = exp2f(st[15]);                                                      \
        lsum += (((e0 + e1) + (e2 + e3)) + ((e4 + e5) + (e6 + e7))) +                   \
                (((e8 + e9) + (e10 + e11)) + ((e12 + e13) + (e14 + e15)));              \
        MKPA(PA0, e0, e1, e2, e3, e4, e5, e6, e7);                                      \
        MKPA(PA1, e8, e9, e10, e11, e12, e13, e14, e15);                                \
    }

// PV for one k-half: pa0 covers k-slice A (V slot pair DA/DB), pa1 slice B (DC/DD).
#define PVHALF(VIMM, DA, DB, DC, DD)                                                    \
    {                                                                                   \
        __builtin_amdgcn_s_setprio(1);                                                  \
        bf16x8 vv;                                                                      \
        FRAG(vv, (VIMM),        DA, DB); o0 = MFMA32(pa0, vv, o0);                      \
        FRAG(vv, (VIMM) + 4096, DA, DB); o1 = MFMA32(pa0, vv, o1);                      \
        FRAG(vv, (VIMM),        DC, DD); o0 = MFMA32(pa1, vv, o0);                      \
        FRAG(vv, (VIMM) + 4096, DC, DD); o1 = MFMA32(pa1, vv, o1);                      \
        __builtin_amdgcn_s_setprio(0);                                                  \
    }

#define CHUNK(BUF, KCL, LAST)                                                           \
    {                                                                                   \
        if (!(LAST)) STAGE((BUF) ^ 1);                                                  \
        u64 ms_ = mwc >> (4 * h);                                                       \
        mwc = mp[(KCL) + 1];                                                            \
        bf16x8 pa0, pa1;                                                                \
        QKHALF((BUF) * 8192,        (u32)ms_,         pa0, pa1);                        \
        PVHALF(16384 + (BUF) * 8192, dof0, dof1, dof2, dof3);                           \
        QKHALF((BUF) * 8192 + 4096, (u32)(ms_ >> 32), pa0, pa1);                        \
        PVHALF(16384 + (BUF) * 8192, dof4, dof5, dof6, dof7);                           \
        __syncthreads();                                                                \
    }

    STAGE(0);
    mwc = mp[0];
    __syncthreads();

    for (int t2 = 0; t2 < 8; ++t2) {
        CHUNK(0, 2 * t2, false);
        CHUNK(1, 2 * t2 + 1, t2 == 7);
    }
#undef STAGE
#undef CHUNK
#undef QKHALF
#undef PVHALF
#undef FRAG
#undef MKPA

    lsum += __shfl_xor(lsum, 32);
    u16* op = (s ? oPb : oPa) + (size_t)(b * 2048 + qb) * 1024 + hh * 64 + l31;
    if (h == 0) {
        float* lp = (s ? lsPb : lsPa);
        lp[(b * 16 + hh) * 2048 + qb + l31] = lsum;
    }
#pragma unroll
    for (int r = 0; r < 16; ++r) {
        int qloc = (r & 3) + 8 * (r >> 2) + 4 * h;
        op[(size_t)qloc * 1024]      = f2bf(o0[r]);
        op[(size_t)qloc * 1024 + 32] = f2bf(o1[r]);
    }
}

// ---------------- combine: Ob = (oA+oB)/(lA+lB), bf16 ----------------
__global__ void combine(const ushort4* __restrict__ pa, const ushort4* __restrict__ pb,
                        const float* __restrict__ la, const float* __restrict__ lb,
                        ushort4* __restrict__ Ob) {
    int i = blockIdx.x * 256 + threadIdx.x;   // 1,048,576 groups of 4 cols
    int row = i >> 8;                          // b*2048 + q
    int col = (i & 255) * 4;
    int hh = col >> 6;
    int b = row >> 11, q = row & 2047;
    ushort4 x = pa[i], y = pb[i];
    int li = (b * 16 + hh) * 2048 + q;
    float rl = 1.0f / (la[li] + lb[li]);
    ushort4 o;
    o.x = f2bf((bf2f(x.x) + bf2f(y.x)) * rl);
    o.y = f2bf((bf2f(x.y) + bf2f(y.y)) * rl);
    o.z = f2bf((bf2f(x.z) + bf2f(y.z)) * rl);
    o.w = f2bf((bf2f(x.w) + bf2f(y.w)) * rl);
    Ob[i] = o;
}

// ---------------- launch ----------------
extern "C" void kernel_launch(void* const* d_in, const int* in_sizes, int n_in,
                              void* d_out, int out_size, void* d_ws, size_t ws_size,
                              hipStream_t stream) {
    (void)in_sizes; (void)n_in; (void)out_size; (void)ws_size;
    const float* inq  = (const float*)d_in[0];
    const float* inkv = (const float*)d_in[1];
    const void*  mask = d_in[2];
    const float* Wq   = (const float*)d_in[3];
    const float* bq   = (const float*)d_in[4];
    const float* Wk   = (const float*)d_in[5];
    const float* bk   = (const float*)d_in[6];
    const float* Wv   = (const float*)d_in[7];
    const float* bv   = (const float*)d_in[8];
    const float* Wo   = (const float*)d_in[9];
    const float* bo   = (const float*)d_in[10];
    float* out = (float*)d_out;

    char* ws = (char*)d_ws;
    int* flag    = (int*)ws;                     // 256 B
    f32x4* lut   = (f32x4*)(ws + 256);           // 256 B (16 x f32x4)
    u16* Aq   = (u16*)(ws + 512);                // 4096x1024 (dead after gemm0 -> oPa)
    u16* Akv  = Aq + 4194304;                    // 4096x1024 (dead after gemm0 -> oPb)
    u16* Wcat = Akv + 4194304;                   // 1152x1024 (dead after gemm0 -> lsP)
    u16* Wot  = Wcat + 1179648;                  // 1024x1024
    u16* Qb   = Wot + 1048576;                   // 4096x1024 (roped, *QSCALE)
    u16* Kbf  = Qb + 4194304;                    // 4096x64 swizzled (+ pad)
    u16* Vtb  = Kbf + 266496;                    // 2x64x2048 swizzled (+ pad)
    u16* Ob   = Vtb + 266496;                    // 4096x1024 (attn out)
    u64* Mb   = (u64*)(Ob + 4194304);            // 131072 words (+8 pad)
    float2* rtbl = (float2*)(Mb + 131080);       // 2048x32 cos/sin

    // partial buffers overlay dead-after-gemm0 regions
    u16* oPa = Aq;
    u16* oPb = Akv;
    float* lsPa = (float*)Wcat;                  // 65536 f32
    float* lsPb = lsPa + 65536;                  // 65536 f32

    detect_mask<<<1, 64, 0, stream>>>((const unsigned char*)mask, flag, (float*)lut);
    prep<<<12672, 256, 0, stream>>>((const float4*)inq, (const float4*)inkv,
                                    (ushort4*)Aq, (ushort4*)Akv,
                                    Wq, Wk, Wv, Wo, Wcat, Wot,
                                    mask, flag, Mb, rtbl);
    gemm_bt<0><<<576, 256, 0, stream>>>(Aq, Akv, Wcat, bq, bk, bv, rtbl,
                                        Qb, Kbf, Vtb, nullptr, 9);
    flash<<<1024, 256, 0, stream>>>(Qb, Kbf, Vtb, Mb, lut, oPa, oPb, lsPa, lsPb);
    combine<<<4096, 256, 0, stream>>>((const ushort4*)oPa, (const ushort4*)oPb,
                                      lsPa, lsPb, (ushort4*)Ob);
    gemm_bt<2><<<512, 256, 0, stream>>>(Ob, nullptr, Wot, bo, nullptr, nullptr, rtbl,
                                        nullptr, nullptr, nullptr, out, 8);
}

// Round 10
// 138.024 us; speedup vs baseline: 1.0426x; 1.0426x over previous
//
#include <hip/hip_runtime.h>

typedef unsigned short u16;
typedef unsigned int u32;
typedef unsigned long long u64;
typedef __bf16 bf16x8 __attribute__((ext_vector_type(8)));
typedef __bf16 bf16x4 __attribute__((ext_vector_type(4)));
typedef u16 u16x8 __attribute__((ext_vector_type(8)));
typedef float f32x4 __attribute__((ext_vector_type(4)));
typedef float f32x16 __attribute__((ext_vector_type(16)));
typedef u32 u32x4 __attribute__((ext_vector_type(4)));

// ---------------- helpers ----------------
__device__ __forceinline__ u16 f2bf(float f) {
    return __builtin_bit_cast(u16, (__bf16)f);   // RNE
}
__device__ __forceinline__ float bf2f(u16 v) {
    u32 u = ((u32)v) << 16;
    return __builtin_bit_cast(float, u);
}

__device__ __forceinline__ void gl_lds16(const void* g, void* l) {
    __builtin_amdgcn_global_load_lds(
        (const __attribute__((address_space(1))) unsigned int*)g,
        (__attribute__((address_space(3))) unsigned int*)l, 16, 0, 0);
}

// log2(e)/8 folded into Q projection; fixed softmax origin m=16 (|s|<~6).
#define QSCALE 0.18033688011112042f

// ---------------- fused prep: bf16 convert | transposes | rope+lut | mask pack -------
// Mask dtype sniffed locally per mask-pack block (2 ballots over first 256 bytes):
// flag 0 = byte(bool), 1 = int32, 2 = float32.
__global__ void prep(const float4* __restrict__ inq, const float4* __restrict__ inkv,
                     ushort4* __restrict__ oAq, ushort4* __restrict__ oAkv,
                     const float* __restrict__ Wq, const float* __restrict__ Wk,
                     const float* __restrict__ Wv, const float* __restrict__ Wo,
                     u16* __restrict__ Wcat, u16* __restrict__ Wot,
                     const void* __restrict__ mask,
                     u64* __restrict__ Mb, float2* __restrict__ rtbl,
                     float* __restrict__ lutg) {
    int bid = blockIdx.x;
    const int tid = threadIdx.x;
    if (bid < 8192) {   // f32 -> bf16 activations
        int i = bid * 256 + tid;
        const float4* src; ushort4* dst; int j;
        if (i < 1048576) { src = inq;  dst = oAq;  j = i; }
        else             { src = inkv; dst = oAkv; j = i - 1048576; }
        float4 f = src[j];
        ushort4 o;
        o.x = f2bf(f.x); o.y = f2bf(f.y); o.z = f2bf(f.z); o.w = f2bf(f.w);
        dst[j] = o;
        return;
    }
    bid -= 8192;
    if (bid < 2176) {   // weight transposes
        const float* src; u16* dst; int C, bx, by;
        if (bid < 1024)      { src = Wq; dst = Wcat;           C = 1024; bx = bid & 31;          by = bid >> 5; }
        else if (bid < 2048) { src = Wo; dst = Wot;            C = 1024; bx = (bid - 1024) & 31; by = (bid - 1024) >> 5; }
        else if (bid < 2112) { src = Wk; dst = Wcat + 1048576; C = 64;   bx = (bid - 2048) & 1;  by = (bid - 2048) >> 1; }
        else                 { src = Wv; dst = Wcat + 1114112; C = 64;   bx = (bid - 2112) & 1;  by = (bid - 2112) >> 1; }
        __shared__ float t[32][33];
        int tx = tid & 31, ty = tid >> 5;
        bx *= 32; by *= 32;
#pragma unroll
        for (int i = 0; i < 4; ++i)
            t[ty + i * 8][tx] = src[(size_t)(by + ty + i * 8) * C + bx + tx];
        __syncthreads();
#pragma unroll
        for (int i = 0; i < 4; ++i)
            dst[(size_t)(bx + ty + i * 8) * 1024 + by + tx] = f2bf(t[tx][ty + i * 8]);
        return;
    }
    bid -= 2176;
    if (bid < 256) {    // rope table (+ mask LUT from block 0)
        if (bid == 0 && tid < 64)
            lutg[tid] = (((tid >> 2) >> (tid & 3)) & 1) ? -16.0f : -100000.0f;
        int i = bid * 256 + tid;
        int pos = i >> 5, j = i & 31;
        float inv = powf(10000.0f, -(float)(2 * j) * (1.0f / 64.0f));
        float s, c;
        sincosf((float)pos * inv, &s, &c);
        rtbl[i] = make_float2(c, s);
        return;
    }
    bid -= 256;
    {   // bit-pack mask, dtype sniffed locally
        __shared__ int sflag;
        if (tid < 64) {
            uchar4 v = ((const uchar4*)mask)[tid];
            u64 bm0 = __ballot(v.x != 0);
            u64 bm1 = __ballot(v.y != 0);
            if (tid == 0) sflag = bm1 ? 0 : (bm0 ? 1 : 2);
        }
        __syncthreads();
        const int flag = sflag;
        int lane = tid & 63;
        for (int wid = bid * 4 + (tid >> 6); wid < 131072; wid += 8192) {
            size_t idx = (size_t)wid * 64 + lane;
            bool v;
            if (flag == 0)      v = ((const unsigned char*)mask)[idx] != 0;
            else if (flag == 1) v = ((const int*)mask)[idx] != 0;
            else                v = ((const float*)mask)[idx] != 0.f;
            u64 bm = __ballot(v);
            if (lane == 0) Mb[wid] = bm;
        }
    }
}

// ---------------- GEMM: C(M=4096, Ntiles*128) = A(M,1024) @ Bt(N,1024)^T -------------
// 64Mx128N, 4 waves, double-buffered LDS, one barrier per K-step.
// MODE 0: fused QKV projection. A/B staged via global_load_lds (pre-swizzled source,
//         linear LDS dest, swizzled reads — rule #21). K/V outputs 8B-XOR-swizzled.
// MODE 2: output projection, fused split-KV combine: A = (oPa+oPb) * 1/(la+lb),
//         reg-staged (load bf16 partials -> combine -> cvt_pk -> swizzled ds_write;
//         head index == K-chunk index, so rl is one scalar per row per step).
//         b2/b3 carry la/lb. B side unchanged (gl_lds). +bo, f32 store.
template <int MODE>
__launch_bounds__(256)
__global__ void gemm_bt(const u16* __restrict__ A0, const u16* __restrict__ A1,
                        const u16* __restrict__ Bt,
                        const float* __restrict__ b1, const float* __restrict__ b2,
                        const float* __restrict__ b3,
                        const float2* __restrict__ rtbl,
                        u16* __restrict__ oQ, u16* __restrict__ oK, u16* __restrict__ oV,
                        float* __restrict__ oF, int Ntiles) {
    __shared__ __align__(16) u16 lA[2][64 * 64];
    __shared__ __align__(16) u16 lB[2][128 * 64];
    const int tid = threadIdx.x, w = tid >> 6, lane = tid & 63;
    const int tm = blockIdx.x / Ntiles, tn = blockIdx.x % Ntiles;
    const int wm = w >> 1, wn = w & 1;
    const int lq = lane & 15, g = lane >> 4, g4 = g << 2;
    const u32 swz = (lane & 7) << 4;
    const u32 bcolg = (16 * g) ^ swz;
    const u16* A = (MODE == 0 && tn == 8) ? A1 : A0;

    // staging thread -> (row rs, 8-elem chunk ch)
    const int rs = tid >> 3, ch = tid & 7;
    const u32 sc = (u32)((ch ^ (rs & 7)) * 8);   // pre-swizzled source offset (gl_lds)
    const u32 lws = (u32)(rs * 128 + (((u32)ch << 4) ^ ((u32)(rs & 7) << 4)));  // ds_write dest

    // B staging pointers (always gl_lds, pre-swizzled source)
    const u16* gB0 = Bt + (size_t)(tn * 128 + rs) * 1024 + sc;
    const u16* gB1 = gB0 + 32 * 1024;
    const u16* gB2 = gB0 + 64 * 1024;
    const u16* gB3 = gB0 + 96 * 1024;

#define GSTAGE_B(BUFI, T)                                                      \
    {                                                                          \
        gl_lds16(gB0 + (T) * 64, (char*)lB + (BUFI) * 16384 + tid * 16);       \
        gl_lds16(gB1 + (T) * 64, (char*)lB + (BUFI) * 16384 + 4096 + tid * 16);\
        gl_lds16(gB2 + (T) * 64, (char*)lB + (BUFI) * 16384 + 8192 + tid * 16);\
        gl_lds16(gB3 + (T) * 64, (char*)lB + (BUFI) * 16384 + 12288 + tid * 16);\
    }

    // A staging: MODE 0 via gl_lds; MODE 2 via reg-staged combine
    const u16* gA0 = A + (size_t)(tm * 64 + rs) * 1024 + sc;
    const u16* gA1 = gA0 + 32 * 1024;
#define GSTAGE_A(BUFI, T)                                                      \
    {                                                                          \
        gl_lds16(gA0 + (T) * 64, (char*)lA + (BUFI) * 8192 + tid * 16);        \
        gl_lds16(gA1 + (T) * 64, (char*)lA + (BUFI) * 8192 + 4096 + tid * 16); \
    }

    // MODE 2 state
    const u16* pa0_ = A0 + (size_t)(tm * 64 + rs) * 1024 + ch * 8;   // oPa row0, linear
    const u16* pb0_ = A1 + (size_t)(tm * 64 + rs) * 1024 + ch * 8;   // oPb row0
    const u16* pa1_ = pa0_ + 32 * 1024;
    const u16* pb1_ = pb0_ + 32 * 1024;
    int li0 = 0, li1 = 0;
    if constexpr (MODE == 2) {
        int row0 = tm * 64 + rs, row1 = row0 + 32;
        li0 = (row0 >> 11) * 32768 + (row0 & 2047);
        li1 = (row1 >> 11) * 32768 + (row1 & 2047);
    }
    u16x8 xa0, xb0, xa1, xb1;
    float rl0 = 0.f, rl1 = 0.f;

#define A_COMB_LOAD(T)                                                         \
    {                                                                          \
        xa0 = *(const u16x8*)(pa0_ + (T) * 64);                                \
        xb0 = *(const u16x8*)(pb0_ + (T) * 64);                                \
        xa1 = *(const u16x8*)(pa1_ + (T) * 64);                                \
        xb1 = *(const u16x8*)(pb1_ + (T) * 64);                                \
        rl0 = 1.0f / (b2[li0 + (T) * 2048] + b3[li0 + (T) * 2048]);            \
        rl1 = 1.0f / (b2[li1 + (T) * 2048] + b3[li1 + (T) * 2048]);            \
    }

#define A_COMB_STORE(BUFI)                                                     \
    {                                                                          \
        u32 w0_[4], w1_[4];                                                    \
        _Pragma("unroll") for (int ii = 0; ii < 4; ++ii) {                     \
            float f0 = (bf2f((u16)xa0[2 * ii]) + bf2f((u16)xb0[2 * ii])) * rl0;        \
            float f1 = (bf2f((u16)xa0[2 * ii + 1]) + bf2f((u16)xb0[2 * ii + 1])) * rl0;\
            asm("v_cvt_pk_bf16_f32 %0, %1, %2" : "=v"(w0_[ii]) : "v"(f0), "v"(f1));    \
            float h0 = (bf2f((u16)xa1[2 * ii]) + bf2f((u16)xb1[2 * ii])) * rl1;        \
            float h1 = (bf2f((u16)xa1[2 * ii + 1]) + bf2f((u16)xb1[2 * ii + 1])) * rl1;\
            asm("v_cvt_pk_bf16_f32 %0, %1, %2" : "=v"(w1_[ii]) : "v"(h0), "v"(h1));    \
        }                                                                      \
        *(u32x4*)((char*)lA + (BUFI) * 8192 + lws) = u32x4{w0_[0], w0_[1], w0_[2], w0_[3]}; \
        *(u32x4*)((char*)lA + (BUFI) * 8192 + 4096 + lws) = u32x4{w1_[0], w1_[1], w1_[2], w1_[3]}; \
    }

    f32x4 acc[2][4] = {};

    // prologue: stage step 0
    GSTAGE_B(0, 0);
    if constexpr (MODE == 0) {
        GSTAGE_A(0, 0);
    } else {
        A_COMB_LOAD(0);
        A_COMB_STORE(0);
    }
    __syncthreads();

#pragma unroll
    for (int t = 0; t < 16; ++t) {
        if (t < 15) {
            GSTAGE_B((t + 1) & 1, t + 1);
            if constexpr (MODE == 0) { GSTAGE_A((t + 1) & 1, t + 1); }
            else                     { A_COMB_LOAD(t + 1); }
        }
        const char* bA = (const char*)lA + (t & 1) * 8192;
        const char* bB = (const char*)lB + (t & 1) * 16384;
#pragma unroll
        for (int kc = 0; kc < 2; ++kc) {
            const u32 col = bcolg ^ (64 * kc);
            bf16x8 af0 = *(const bf16x8*)(bA + (wm * 32 + lq) * 128 + col);
            bf16x8 af1 = *(const bf16x8*)(bA + (wm * 32 + 16 + lq) * 128 + col);
            bf16x8 bg0 = *(const bf16x8*)(bB + (wn * 64 + lq) * 128 + col);
            bf16x8 bg1 = *(const bf16x8*)(bB + (wn * 64 + 16 + lq) * 128 + col);
            bf16x8 bg2 = *(const bf16x8*)(bB + (wn * 64 + 32 + lq) * 128 + col);
            bf16x8 bg3 = *(const bf16x8*)(bB + (wn * 64 + 48 + lq) * 128 + col);
            acc[0][0] = __builtin_amdgcn_mfma_f32_16x16x32_bf16(af0, bg0, acc[0][0], 0, 0, 0);
            acc[0][1] = __builtin_amdgcn_mfma_f32_16x16x32_bf16(af0, bg1, acc[0][1], 0, 0, 0);
            acc[0][2] = __builtin_amdgcn_mfma_f32_16x16x32_bf16(af0, bg2, acc[0][2], 0, 0, 0);
            acc[0][3] = __builtin_amdgcn_mfma_f32_16x16x32_bf16(af0, bg3, acc[0][3], 0, 0, 0);
            acc[1][0] = __builtin_amdgcn_mfma_f32_16x16x32_bf16(af1, bg0, acc[1][0], 0, 0, 0);
            acc[1][1] = __builtin_amdgcn_mfma_f32_16x16x32_bf16(af1, bg1, acc[1][1], 0, 0, 0);
            acc[1][2] = __builtin_amdgcn_mfma_f32_16x16x32_bf16(af1, bg2, acc[1][2], 0, 0, 0);
            acc[1][3] = __builtin_amdgcn_mfma_f32_16x16x32_bf16(af1, bg3, acc[1][3], 0, 0, 0);
        }
        if (t < 15) {
            if constexpr (MODE == 2) { A_COMB_STORE((t + 1) & 1); }
        }
        __syncthreads();
    }
#undef GSTAGE_B
#undef GSTAGE_A
#undef A_COMB_LOAD
#undef A_COMB_STORE

    // epilogue
#pragma unroll
    for (int mi = 0; mi < 2; ++mi) {
#pragma unroll
        for (int ni = 0; ni < 4; ++ni) {
#pragma unroll
            for (int r = 0; r < 4; ++r) {
                int grow = tm * 64 + wm * 32 + mi * 16 + g4 + r;
                float v = acc[mi][ni][r];
                if constexpr (MODE == 0) {
                    int pos = grow & 2047;
                    if (tn < 8) {
                        int gcol = tn * 128 + wn * 64 + ni * 16 + lq;
                        v += b1[gcol];
                        float2 cs = rtbl[pos * 32 + ((gcol & 63) >> 1)];
                        float prt = __shfl_xor(v, 1);
                        v = (gcol & 1) ? (v * cs.x + prt * cs.y) : (v * cs.x - prt * cs.y);
                        v *= QSCALE;
                        oQ[(size_t)grow * 1024 + gcol] = f2bf(v);
                    } else {
                        int lc = wn * 64 + ni * 16 + lq;
                        if (lc < 64) {   // K: 8B-block XOR swizzle within 128B row
                            v += b2[lc];
                            float2 cs = rtbl[pos * 32 + (lc >> 1)];
                            float prt = __shfl_xor(v, 1);
                            v = (lc & 1) ? (v * cs.x + prt * cs.y) : (v * cs.x - prt * cs.y);
                            oK[(size_t)grow * 64 + ((((u32)lc >> 2) ^ ((u32)grow & 15)) << 2)
                               + (lc & 3)] = f2bf(v);
                        } else {         // V^T [b][d][kk], swizzled within each 64-kk chunk
                            int d = lc - 64;
                            v += b3[d];
                            int b = grow >> 11, ll = grow & 2047;
                            int cc = ll & 63;
                            oV[((size_t)(b * 64 + d)) * 2048 + (ll & ~63)
                               + ((((u32)cc >> 2) ^ ((u32)d & 15)) << 2) + (cc & 3)] = f2bf(v);
                        }
                    }
                } else {
                    int gcol = tn * 128 + wn * 64 + ni * 16 + lq;
                    oF[(size_t)grow * 1024 + gcol] = v + b1[gcol];
                }
            }
        }
    }
}

// ---------------- flash attention: 32x32 MFMA, in-reg P, 2-way split-KV -------------
// grid: b*512 + hh*32 + qt*2 + s. 4 waves x 32 q. Each block: 16 KV chunks (1024 kv).
// Fixed-origin softmax => partials combine linearly (combine fused into gemm_bt<2>).
// Unchanged from round 9 (67.8 us stable; occupancy is no longer the binding limit).
#define MFMA32(A, B, C) __builtin_amdgcn_mfma_f32_32x32x16_bf16(A, B, C, 0, 0, 0)

__launch_bounds__(256, 4)
__global__ void flash(const u16* __restrict__ Qb, const u16* __restrict__ Kb,
                      const u16* __restrict__ Vt, const u64* __restrict__ Mb,
                      const f32x4* __restrict__ lut,
                      u16* __restrict__ oPa, u16* __restrict__ oPb,
                      float* __restrict__ lsPa, float* __restrict__ lsPb) {
    __shared__ __align__(16) u16 lK[2][64 * 64];   // [kk][d], 8B-XOR swizzled
    __shared__ __align__(16) u16 lV[2][64 * 64];   // [d][kk], 8B-XOR swizzled
    __shared__ f32x4 slut[16];
    const int tid = threadIdx.x, w = tid >> 6, lane = tid & 63;
    const int s = blockIdx.x & 1, qt = (blockIdx.x >> 1) & 15;
    const int hh = (blockIdx.x >> 5) & 15, b = blockIdx.x >> 9;
    const int qb = qt * 128 + w * 32;
    const int l31 = lane & 31, h = lane >> 5, l15 = lane & 15;

    if (tid < 16) slut[tid] = lut[tid];

    bf16x8 qf0, qf1, qf2, qf3;
    {
        const u16* qp = Qb + (size_t)(b * 2048 + qb + l31) * 1024 + hh * 64 + h * 8;
        qf0 = *(const bf16x8*)(qp);
        qf1 = *(const bf16x8*)(qp + 16);
        qf2 = *(const bf16x8*)(qp + 32);
        qf3 = *(const bf16x8*)(qp + 48);
    }

    const u64* mp = Mb + (size_t)(b * 2048 + qb + l31) * 32 + s * 16;

    u32 dof0 = ((u32)(2 * h) ^ l15) << 3,      dof1 = ((u32)(2 * h + 1) ^ l15) << 3;
    u32 dof2 = ((u32)(4 + 2 * h) ^ l15) << 3,  dof3 = ((u32)(5 + 2 * h) ^ l15) << 3;
    u32 dof4 = ((u32)(8 + 2 * h) ^ l15) << 3,  dof5 = ((u32)(9 + 2 * h) ^ l15) << 3;
    u32 dof6 = ((u32)(12 + 2 * h) ^ l15) << 3, dof7 = ((u32)(13 + 2 * h) ^ l15) << 3;
    const char* kvbase = (const char*)lK + l31 * 128;

    const u16* pK = Kb + (size_t)b * 131072 + (size_t)s * 65536 + tid * 8;
    const u16* pV = Vt + (size_t)(b * 64 + (tid >> 3)) * 2048 + s * 1024 + (tid & 7) * 8;
    const u16* pV2 = pV + 32 * 2048;

#define STAGE(BUF)                                                       \
    {                                                                    \
        gl_lds16(pK,        (char*)lK + (BUF) * 8192 + tid * 16);        \
        gl_lds16(pK + 2048, (char*)lK + (BUF) * 8192 + 4096 + tid * 16); \
        gl_lds16(pV,        (char*)lV + (BUF) * 8192 + tid * 16);        \
        gl_lds16(pV2,       (char*)lV + (BUF) * 8192 + 4096 + tid * 16); \
        pK += 4096; pV += 64; pV2 += 64;                                 \
    }

    f32x16 o0 = {}, o1 = {};
    float lsum = 0.f;
    u64 mwc;

#define FRAG(DST, IMM, OFA, OFB)                                             \
    {                                                                        \
        bf16x4 lo_ = *(const bf16x4*)(kvbase + (IMM) + (OFA));               \
        bf16x4 hi_ = *(const bf16x4*)(kvbase + (IMM) + (OFB));               \
        DST = __builtin_shufflevector(lo_, hi_, 0, 1, 2, 3, 4, 5, 6, 7);     \
    }

#define MKPA(PA, E0, E1, E2, E3, E4, E5, E6, E7)                             \
    {                                                                        \
        u32 x0_, x1_, y0_, y1_;                                              \
        asm("v_cvt_pk_bf16_f32 %0, %1, %2" : "=v"(x0_) : "v"(E0), "v"(E1));  \
        asm("v_cvt_pk_bf16_f32 %0, %1, %2" : "=v"(x1_) : "v"(E2), "v"(E3));  \
        asm("v_cvt_pk_bf16_f32 %0, %1, %2" : "=v"(y0_) : "v"(E4), "v"(E5));  \
        asm("v_cvt_pk_bf16_f32 %0, %1, %2" : "=v"(y1_) : "v"(E6), "v"(E7));  \
        asm("v_permlane32_swap_b32 %0, %1" : "+v"(x0_), "+v"(y0_));          \
        asm("v_permlane32_swap_b32 %0, %1" : "+v"(x1_), "+v"(y1_));          \
        u32x4 t_ = {x0_, x1_, y0_, y1_};                                     \
        PA = __builtin_bit_cast(bf16x8, t_);                                 \
    }

#define QKHALF(KIMM, MS, PA0, PA1)                                                      \
    {                                                                                   \
        f32x16 st;                                                                      \
        {                                                                               \
            f32x4 c0_ = slut[(u32)(MS) & 15];                                           \
            f32x4 c1_ = slut[(u32)((MS) >> 8) & 15];                                    \
            f32x4 c2_ = slut[(u32)((MS) >> 16) & 15];                                   \
            f32x4 c3_ = slut[(u32)((MS) >> 24) & 15];                                   \
            st[0] = c0_[0]; st[1] = c0_[1]; st[2] = c0_[2]; st[3] = c0_[3];             \
            st[4] = c1_[0]; st[5] = c1_[1]; st[6] = c1_[2]; st[7] = c1_[3];             \
            st[8] = c2_[0]; st[9] = c2_[1]; st[10] = c2_[2]; st[11] = c2_[3];           \
            st[12] = c3_[0]; st[13] = c3_[1]; st[14] = c3_[2]; st[15] = c3_[3];         \
        }                                                                               \
        __builtin_amdgcn_s_setprio(1);                                                  \
        {                                                                               \
            bf16x8 kf;                                                                  \
            FRAG(kf, (KIMM), dof0, dof1); st = MFMA32(kf, qf0, st);                     \
            FRAG(kf, (KIMM), dof2, dof3); st = MFMA32(kf, qf1, st);                     \
            FRAG(kf, (KIMM), dof4, dof5); st = MFMA32(kf, qf2, st);                     \
            FRAG(kf, (KIMM), dof6, dof7); st = MFMA32(kf, qf3, st);                     \
        }                                                                               \
        __builtin_amdgcn_s_setprio(0);                                                  \
        float e0 = exp2f(st[0]), e1 = exp2f(st[1]), e2 = exp2f(st[2]),                  \
              e3 = exp2f(st[3]), e4 = exp2f(st[4]), e5 = exp2f(st[5]),                  \
              e6 = exp2f(st[6]), e7 = exp2f(st[7]), e8 = exp2f(st[8]),                  \
              e9 = exp2f(st[9]), e10 = exp2f(st[10]), e11 = exp2f(st[11]),              \
              e12 = exp2f(st[12]), e13 = exp2f(st[13]), e14 = exp2f(st[14]),            \
              e15 = exp2f(st[15]);                                                      \
        lsum += (((e0 + e1) + (e2 + e3)) + ((e4 + e5) + (e6 + e7))) +                   \
                (((e8 + e9) + (e10 + e11)) + ((e12 + e13) + (e14 + e15)));              \
        MKPA(PA0, e0, e1, e2, e3, e4, e5, e6, e7);                                      \
        MKPA(PA1, e8, e9, e10, e11, e12, e13, e14, e15);                                \
    }

#define PVHALF(VIMM, DA, DB, DC, DD)                                                    \
    {                                                                                   \
        __builtin_amdgcn_s_setprio(1);                                                  \
        bf16x8 vv;                                                                      \
        FRAG(vv, (VIMM),        DA, DB); o0 = MFMA32(pa0, vv, o0);                      \
        FRAG(vv, (VIMM) + 4096, DA, DB); o1 = MFMA32(pa0, vv, o1);                      \
        FRAG(vv, (VIMM),        DC, DD); o0 = MFMA32(pa1, vv, o0);                      \
        FRAG(vv, (VIMM) + 4096, DC, DD); o1 = MFMA32(pa1, vv, o1);                      \
        __builtin_amdgcn_s_setprio(0);                                                  \
    }

#define CHUNK(BUF, KCL, LAST)                                                           \
    {                                                                                   \
        if (!(LAST)) STAGE((BUF) ^ 1);                                                  \
        u64 ms_ = mwc >> (4 * h);                                                       \
        mwc = mp[(KCL) + 1];                                                            \
        bf16x8 pa0, pa1;                                                                \
        QKHALF((BUF) * 8192,        (u32)ms_,         pa0, pa1);                        \
        PVHALF(16384 + (BUF) * 8192, dof0, dof1, dof2, dof3);                           \
        QKHALF((BUF) * 8192 + 4096, (u32)(ms_ >> 32), pa0, pa1);                        \
        PVHALF(16384 + (BUF) * 8192, dof4, dof5, dof6, dof7);                           \
        __syncthreads();                                                                \
    }

    STAGE(0);
    mwc = mp[0];
    __syncthreads();

    for (int t2 = 0; t2 < 8; ++t2) {
        CHUNK(0, 2 * t2, false);
        CHUNK(1, 2 * t2 + 1, t2 == 7);
    }
#undef STAGE
#undef CHUNK
#undef QKHALF
#undef PVHALF
#undef FRAG
#undef MKPA

    lsum += __shfl_xor(lsum, 32);
    u16* op = (s ? oPb : oPa) + (size_t)(b * 2048 + qb) * 1024 + hh * 64 + l31;
    if (h == 0) {
        float* lp = (s ? lsPb : lsPa);
        lp[(b * 16 + hh) * 2048 + qb + l31] = lsum;
    }
#pragma unroll
    for (int r = 0; r < 16; ++r) {
        int qloc = (r & 3) + 8 * (r >> 2) + 4 * h;
        op[(size_t)qloc * 1024]      = f2bf(o0[r]);
        op[(size_t)qloc * 1024 + 32] = f2bf(o1[r]);
    }
}

// ---------------- launch ----------------
extern "C" void kernel_launch(void* const* d_in, const int* in_sizes, int n_in,
                              void* d_out, int out_size, void* d_ws, size_t ws_size,
                              hipStream_t stream) {
    (void)in_sizes; (void)n_in; (void)out_size; (void)ws_size;
    const float* inq  = (const float*)d_in[0];
    const float* inkv = (const float*)d_in[1];
    const void*  mask = d_in[2];
    const float* Wq   = (const float*)d_in[3];
    const float* bq   = (const float*)d_in[4];
    const float* Wk   = (const float*)d_in[5];
    const float* bk   = (const float*)d_in[6];
    const float* Wv   = (const float*)d_in[7];
    const float* bv   = (const float*)d_in[8];
    const float* Wo   = (const float*)d_in[9];
    const float* bo   = (const float*)d_in[10];
    float* out = (float*)d_out;

    char* ws = (char*)d_ws;
    f32x4* lut   = (f32x4*)(ws + 256);           // 256 B (16 x f32x4)
    u16* Aq   = (u16*)(ws + 512);                // 4096x1024 (dead after gemm0 -> oPa)
    u16* Akv  = Aq + 4194304;                    // 4096x1024 (dead after gemm0 -> oPb)
    u16* Wcat = Akv + 4194304;                   // 1152x1024 (dead after gemm0 -> lsP)
    u16* Wot  = Wcat + 1179648;                  // 1024x1024
    u16* Qb   = Wot + 1048576;                   // 4096x1024 (roped, *QSCALE)
    u16* Kbf  = Qb + 4194304;                    // 4096x64 swizzled (+ pad)
    u16* Vtb  = Kbf + 266496;                    // 2x64x2048 swizzled (+ pad)
    u16* Ob   = Vtb + 266496;                    // (unused now; kept for layout)
    u64* Mb   = (u64*)(Ob + 4194304);            // 131072 words (+8 pad)
    float2* rtbl = (float2*)(Mb + 131080);       // 2048x32 cos/sin

    // partial buffers overlay dead-after-gemm0 regions
    u16* oPa = Aq;
    u16* oPb = Akv;
    float* lsPa = (float*)Wcat;                  // 65536 f32
    float* lsPb = lsPa + 65536;                  // 65536 f32

    prep<<<12672, 256, 0, stream>>>((const float4*)inq, (const float4*)inkv,
                                    (ushort4*)Aq, (ushort4*)Akv,
                                    Wq, Wk, Wv, Wo, Wcat, Wot,
                                    mask, Mb, rtbl, (float*)lut);
    gemm_bt<0><<<576, 256, 0, stream>>>(Aq, Akv, Wcat, bq, bk, bv, rtbl,
                                        Qb, Kbf, Vtb, nullptr, 9);
    flash<<<1024, 256, 0, stream>>>(Qb, Kbf, Vtb, Mb, lut, oPa, oPb, lsPa, lsPb);
    gemm_bt<2><<<512, 256, 0, stream>>>(oPa, oPb, Wot, bo, lsPa, lsPb, rtbl,
                                        nullptr, nullptr, nullptr, out, 8);
}

// Round 11
// 135.654 us; speedup vs baseline: 1.0608x; 1.0175x over previous
//
#include <hip/hip_runtime.h>

typedef unsigned short u16;
typedef unsigned int u32;
typedef unsigned long long u64;
typedef __bf16 bf16x8 __attribute__((ext_vector_type(8)));
typedef u16 u16x8 __attribute__((ext_vector_type(8)));
typedef float f32x4 __attribute__((ext_vector_type(4)));
typedef float f32x16 __attribute__((ext_vector_type(16)));
typedef u32 u32x4 __attribute__((ext_vector_type(4)));

// ---------------- helpers ----------------
__device__ __forceinline__ u16 f2bf(float f) {
    return __builtin_bit_cast(u16, (__bf16)f);   // RNE
}
__device__ __forceinline__ float bf2f(u16 v) {
    u32 u = ((u32)v) << 16;
    return __builtin_bit_cast(float, u);
}

__device__ __forceinline__ void gl_lds16(const void* g, void* l) {
    __builtin_amdgcn_global_load_lds(
        (const __attribute__((address_space(1))) unsigned int*)g,
        (__attribute__((address_space(3))) unsigned int*)l, 16, 0, 0);
}

// log2(e)/8 folded into Q projection; fixed softmax origin m=16 (|s|<~6).
#define QSCALE 0.18033688011112042f

// ---------------- fused prep: bf16 convert | transposes | rope+lut | mask pack -------
__global__ void prep(const float4* __restrict__ inq, const float4* __restrict__ inkv,
                     ushort4* __restrict__ oAq, ushort4* __restrict__ oAkv,
                     const float* __restrict__ Wq, const float* __restrict__ Wk,
                     const float* __restrict__ Wv, const float* __restrict__ Wo,
                     u16* __restrict__ Wcat, u16* __restrict__ Wot,
                     const void* __restrict__ mask,
                     u64* __restrict__ Mb, float2* __restrict__ rtbl,
                     float* __restrict__ lutg) {
    int bid = blockIdx.x;
    const int tid = threadIdx.x;
    if (bid < 8192) {   // f32 -> bf16 activations
        int i = bid * 256 + tid;
        const float4* src; ushort4* dst; int j;
        if (i < 1048576) { src = inq;  dst = oAq;  j = i; }
        else             { src = inkv; dst = oAkv; j = i - 1048576; }
        float4 f = src[j];
        ushort4 o;
        o.x = f2bf(f.x); o.y = f2bf(f.y); o.z = f2bf(f.z); o.w = f2bf(f.w);
        dst[j] = o;
        return;
    }
    bid -= 8192;
    if (bid < 2176) {   // weight transposes
        const float* src; u16* dst; int C, bx, by;
        if (bid < 1024)      { src = Wq; dst = Wcat;           C = 1024; bx = bid & 31;          by = bid >> 5; }
        else if (bid < 2048) { src = Wo; dst = Wot;            C = 1024; bx = (bid - 1024) & 31; by = (bid - 1024) >> 5; }
        else if (bid < 2112) { src = Wk; dst = Wcat + 1048576; C = 64;   bx = (bid - 2048) & 1;  by = (bid - 2048) >> 1; }
        else                 { src = Wv; dst = Wcat + 1114112; C = 64;   bx = (bid - 2112) & 1;  by = (bid - 2112) >> 1; }
        __shared__ float t[32][33];
        int tx = tid & 31, ty = tid >> 5;
        bx *= 32; by *= 32;
#pragma unroll
        for (int i = 0; i < 4; ++i)
            t[ty + i * 8][tx] = src[(size_t)(by + ty + i * 8) * C + bx + tx];
        __syncthreads();
#pragma unroll
        for (int i = 0; i < 4; ++i)
            dst[(size_t)(bx + ty + i * 8) * 1024 + by + tx] = f2bf(t[tx][ty + i * 8]);
        return;
    }
    bid -= 2176;
    if (bid < 256) {    // rope table (+ mask LUT from block 0)
        if (bid == 0 && tid < 64)
            lutg[tid] = (((tid >> 2) >> (tid & 3)) & 1) ? -16.0f : -100000.0f;
        int i = bid * 256 + tid;
        int pos = i >> 5, j = i & 31;
        float inv = powf(10000.0f, -(float)(2 * j) * (1.0f / 64.0f));
        float s, c;
        sincosf((float)pos * inv, &s, &c);
        rtbl[i] = make_float2(c, s);
        return;
    }
    bid -= 256;
    {   // bit-pack mask, dtype sniffed locally
        __shared__ int sflag;
        if (tid < 64) {
            uchar4 v = ((const uchar4*)mask)[tid];
            u64 bm0 = __ballot(v.x != 0);
            u64 bm1 = __ballot(v.y != 0);
            if (tid == 0) sflag = bm1 ? 0 : (bm0 ? 1 : 2);
        }
        __syncthreads();
        const int flag = sflag;
        int lane = tid & 63;
        for (int wid = bid * 4 + (tid >> 6); wid < 131072; wid += 8192) {
            size_t idx = (size_t)wid * 64 + lane;
            bool v;
            if (flag == 0)      v = ((const unsigned char*)mask)[idx] != 0;
            else if (flag == 1) v = ((const int*)mask)[idx] != 0;
            else                v = ((const float*)mask)[idx] != 0.f;
            u64 bm = __ballot(v);
            if (lane == 0) Mb[wid] = bm;
        }
    }
}

// ---------------- GEMM: C(M=4096, Ntiles*128) = A(M,1024) @ Bt(N,1024)^T -------------
// 64Mx128N, 4 waves, double-buffered LDS, one barrier per K-step.
// MODE 0: fused QKV projection. K/V outputs stored in 16B-slot XOR-swizzled global
//         layouts (slot = 8 bf16; slot' = slot ^ (row&7)) so flash reads are single
//         ds_read_b128 per MFMA fragment (gemm-proven: zero bank conflicts).
// MODE 2: output projection, fused split-KV combine (A = (oPa+oPb)/(la+lb)).
template <int MODE>
__launch_bounds__(256)
__global__ void gemm_bt(const u16* __restrict__ A0, const u16* __restrict__ A1,
                        const u16* __restrict__ Bt,
                        const float* __restrict__ b1, const float* __restrict__ b2,
                        const float* __restrict__ b3,
                        const float2* __restrict__ rtbl,
                        u16* __restrict__ oQ, u16* __restrict__ oK, u16* __restrict__ oV,
                        float* __restrict__ oF, int Ntiles) {
    __shared__ __align__(16) u16 lA[2][64 * 64];
    __shared__ __align__(16) u16 lB[2][128 * 64];
    const int tid = threadIdx.x, w = tid >> 6, lane = tid & 63;
    const int tm = blockIdx.x / Ntiles, tn = blockIdx.x % Ntiles;
    const int wm = w >> 1, wn = w & 1;
    const int lq = lane & 15, g = lane >> 4, g4 = g << 2;
    const u32 swz = (lane & 7) << 4;
    const u32 bcolg = (16 * g) ^ swz;
    const u16* A = (MODE == 0 && tn == 8) ? A1 : A0;

    // staging thread -> (row rs, 8-elem chunk ch)
    const int rs = tid >> 3, ch = tid & 7;
    const u32 sc = (u32)((ch ^ (rs & 7)) * 8);   // pre-swizzled source offset (gl_lds)
    const u32 lws = (u32)(rs * 128 + (((u32)ch << 4) ^ ((u32)(rs & 7) << 4)));  // ds_write dest

    const u16* gB0 = Bt + (size_t)(tn * 128 + rs) * 1024 + sc;
    const u16* gB1 = gB0 + 32 * 1024;
    const u16* gB2 = gB0 + 64 * 1024;
    const u16* gB3 = gB0 + 96 * 1024;

#define GSTAGE_B(BUFI, T)                                                      \
    {                                                                          \
        gl_lds16(gB0 + (T) * 64, (char*)lB + (BUFI) * 16384 + tid * 16);       \
        gl_lds16(gB1 + (T) * 64, (char*)lB + (BUFI) * 16384 + 4096 + tid * 16);\
        gl_lds16(gB2 + (T) * 64, (char*)lB + (BUFI) * 16384 + 8192 + tid * 16);\
        gl_lds16(gB3 + (T) * 64, (char*)lB + (BUFI) * 16384 + 12288 + tid * 16);\
    }

    const u16* gA0 = A + (size_t)(tm * 64 + rs) * 1024 + sc;
    const u16* gA1 = gA0 + 32 * 1024;
#define GSTAGE_A(BUFI, T)                                                      \
    {                                                                          \
        gl_lds16(gA0 + (T) * 64, (char*)lA + (BUFI) * 8192 + tid * 16);        \
        gl_lds16(gA1 + (T) * 64, (char*)lA + (BUFI) * 8192 + 4096 + tid * 16); \
    }

    // MODE 2 state
    const u16* pa0_ = A0 + (size_t)(tm * 64 + rs) * 1024 + ch * 8;
    const u16* pb0_ = A1 + (size_t)(tm * 64 + rs) * 1024 + ch * 8;
    const u16* pa1_ = pa0_ + 32 * 1024;
    const u16* pb1_ = pb0_ + 32 * 1024;
    int li0 = 0, li1 = 0;
    if constexpr (MODE == 2) {
        int row0 = tm * 64 + rs, row1 = row0 + 32;
        li0 = (row0 >> 11) * 32768 + (row0 & 2047);
        li1 = (row1 >> 11) * 32768 + (row1 & 2047);
    }
    u16x8 xa0, xb0, xa1, xb1;
    float rl0 = 0.f, rl1 = 0.f;

#define A_COMB_LOAD(T)                                                         \
    {                                                                          \
        xa0 = *(const u16x8*)(pa0_ + (T) * 64);                                \
        xb0 = *(const u16x8*)(pb0_ + (T) * 64);                                \
        xa1 = *(const u16x8*)(pa1_ + (T) * 64);                                \
        xb1 = *(const u16x8*)(pb1_ + (T) * 64);                                \
        rl0 = 1.0f / (b2[li0 + (T) * 2048] + b3[li0 + (T) * 2048]);            \
        rl1 = 1.0f / (b2[li1 + (T) * 2048] + b3[li1 + (T) * 2048]);            \
    }

#define A_COMB_STORE(BUFI)                                                     \
    {                                                                          \
        u32 w0_[4], w1_[4];                                                    \
        _Pragma("unroll") for (int ii = 0; ii < 4; ++ii) {                     \
            float f0 = (bf2f((u16)xa0[2 * ii]) + bf2f((u16)xb0[2 * ii])) * rl0;        \
            float f1 = (bf2f((u16)xa0[2 * ii + 1]) + bf2f((u16)xb0[2 * ii + 1])) * rl0;\
            asm("v_cvt_pk_bf16_f32 %0, %1, %2" : "=v"(w0_[ii]) : "v"(f0), "v"(f1));    \
            float h0 = (bf2f((u16)xa1[2 * ii]) + bf2f((u16)xb1[2 * ii])) * rl1;        \
            float h1 = (bf2f((u16)xa1[2 * ii + 1]) + bf2f((u16)xb1[2 * ii + 1])) * rl1;\
            asm("v_cvt_pk_bf16_f32 %0, %1, %2" : "=v"(w1_[ii]) : "v"(h0), "v"(h1));    \
        }                                                                      \
        *(u32x4*)((char*)lA + (BUFI) * 8192 + lws) = u32x4{w0_[0], w0_[1], w0_[2], w0_[3]}; \
        *(u32x4*)((char*)lA + (BUFI) * 8192 + 4096 + lws) = u32x4{w1_[0], w1_[1], w1_[2], w1_[3]}; \
    }

    f32x4 acc[2][4] = {};

    GSTAGE_B(0, 0);
    if constexpr (MODE == 0) {
        GSTAGE_A(0, 0);
    } else {
        A_COMB_LOAD(0);
        A_COMB_STORE(0);
    }
    __syncthreads();

#pragma unroll
    for (int t = 0; t < 16; ++t) {
        if (t < 15) {
            GSTAGE_B((t + 1) & 1, t + 1);
            if constexpr (MODE == 0) { GSTAGE_A((t + 1) & 1, t + 1); }
            else                     { A_COMB_LOAD(t + 1); }
        }
        const char* bA = (const char*)lA + (t & 1) * 8192;
        const char* bB = (const char*)lB + (t & 1) * 16384;
#pragma unroll
        for (int kc = 0; kc < 2; ++kc) {
            const u32 col = bcolg ^ (64 * kc);
            bf16x8 af0 = *(const bf16x8*)(bA + (wm * 32 + lq) * 128 + col);
            bf16x8 af1 = *(const bf16x8*)(bA + (wm * 32 + 16 + lq) * 128 + col);
            bf16x8 bg0 = *(const bf16x8*)(bB + (wn * 64 + lq) * 128 + col);
            bf16x8 bg1 = *(const bf16x8*)(bB + (wn * 64 + 16 + lq) * 128 + col);
            bf16x8 bg2 = *(const bf16x8*)(bB + (wn * 64 + 32 + lq) * 128 + col);
            bf16x8 bg3 = *(const bf16x8*)(bB + (wn * 64 + 48 + lq) * 128 + col);
            acc[0][0] = __builtin_amdgcn_mfma_f32_16x16x32_bf16(af0, bg0, acc[0][0], 0, 0, 0);
            acc[0][1] = __builtin_amdgcn_mfma_f32_16x16x32_bf16(af0, bg1, acc[0][1], 0, 0, 0);
            acc[0][2] = __builtin_amdgcn_mfma_f32_16x16x32_bf16(af0, bg2, acc[0][2], 0, 0, 0);
            acc[0][3] = __builtin_amdgcn_mfma_f32_16x16x32_bf16(af0, bg3, acc[0][3], 0, 0, 0);
            acc[1][0] = __builtin_amdgcn_mfma_f32_16x16x32_bf16(af1, bg0, acc[1][0], 0, 0, 0);
            acc[1][1] = __builtin_amdgcn_mfma_f32_16x16x32_bf16(af1, bg1, acc[1][1], 0, 0, 0);
            acc[1][2] = __builtin_amdgcn_mfma_f32_16x16x32_bf16(af1, bg2, acc[1][2], 0, 0, 0);
            acc[1][3] = __builtin_amdgcn_mfma_f32_16x16x32_bf16(af1, bg3, acc[1][3], 0, 0, 0);
        }
        if (t < 15) {
            if constexpr (MODE == 2) { A_COMB_STORE((t + 1) & 1); }
        }
        __syncthreads();
    }
#undef GSTAGE_B
#undef GSTAGE_A
#undef A_COMB_LOAD
#undef A_COMB_STORE

    // epilogue
#pragma unroll
    for (int mi = 0; mi < 2; ++mi) {
#pragma unroll
        for (int ni = 0; ni < 4; ++ni) {
#pragma unroll
            for (int r = 0; r < 4; ++r) {
                int grow = tm * 64 + wm * 32 + mi * 16 + g4 + r;
                float v = acc[mi][ni][r];
                if constexpr (MODE == 0) {
                    int pos = grow & 2047;
                    if (tn < 8) {
                        int gcol = tn * 128 + wn * 64 + ni * 16 + lq;
                        v += b1[gcol];
                        float2 cs = rtbl[pos * 32 + ((gcol & 63) >> 1)];
                        float prt = __shfl_xor(v, 1);
                        v = (gcol & 1) ? (v * cs.x + prt * cs.y) : (v * cs.x - prt * cs.y);
                        v *= QSCALE;
                        oQ[(size_t)grow * 1024 + gcol] = f2bf(v);
                    } else {
                        int lc = wn * 64 + ni * 16 + lq;
                        if (lc < 64) {   // K: 16B-slot XOR swizzle within 128B row
                            v += b2[lc];
                            float2 cs = rtbl[pos * 32 + (lc >> 1)];
                            float prt = __shfl_xor(v, 1);
                            v = (lc & 1) ? (v * cs.x + prt * cs.y) : (v * cs.x - prt * cs.y);
                            oK[(size_t)grow * 64 + ((((u32)lc >> 3) ^ ((u32)grow & 7)) << 3)
                               + (lc & 7)] = f2bf(v);
                        } else {         // V^T [b][d][kk], 16B-slot swizzle per 64-kk chunk
                            int d = lc - 64;
                            v += b3[d];
                            int b = grow >> 11, ll = grow & 2047;
                            int cc = ll & 63;
                            oV[((size_t)(b * 64 + d)) * 2048 + (ll & ~63)
                               + ((((u32)cc >> 3) ^ ((u32)d & 7)) << 3) + (cc & 7)] = f2bf(v);
                        }
                    }
                } else {
                    int gcol = tn * 128 + wn * 64 + ni * 16 + lq;
                    oF[(size_t)grow * 1024 + gcol] = v + b1[gcol];
                }
            }
        }
    }
}

// ---------------- flash attention: 32x32 MFMA, in-reg P, 2-way split-KV -------------
// grid: b*512 + hh*32 + qt*2 + s. 4 waves x 32 q. Each block: 16 KV chunks (1024 kv).
// 16B-slot XOR-swizzled K/V layouts: each MFMA fragment = ONE ds_read_b128
// (gemm-proven zero-conflict pattern; replaces 2x ds_read_b64 + shufflevector).
#define MFMA32(A, B, C) __builtin_amdgcn_mfma_f32_32x32x16_bf16(A, B, C, 0, 0, 0)

__launch_bounds__(256, 4)
__global__ void flash(const u16* __restrict__ Qb, const u16* __restrict__ Kb,
                      const u16* __restrict__ Vt, const u64* __restrict__ Mb,
                      const f32x4* __restrict__ lut,
                      u16* __restrict__ oPa, u16* __restrict__ oPb,
                      float* __restrict__ lsPa, float* __restrict__ lsPb) {
    __shared__ __align__(16) u16 lK[2][64 * 64];   // [kk][d], 16B-slot swizzled
    __shared__ __align__(16) u16 lV[2][64 * 64];   // [d][kk], 16B-slot swizzled
    __shared__ f32x4 slut[16];
    const int tid = threadIdx.x, w = tid >> 6, lane = tid & 63;
    const int s = blockIdx.x & 1, qt = (blockIdx.x >> 1) & 15;
    const int hh = (blockIdx.x >> 5) & 15, b = blockIdx.x >> 9;
    const int qb = qt * 128 + w * 32;
    const int l31 = lane & 31, h = lane >> 5;

    if (tid < 16) slut[tid] = lut[tid];

    bf16x8 qf0, qf1, qf2, qf3;
    {
        const u16* qp = Qb + (size_t)(b * 2048 + qb + l31) * 1024 + hh * 64 + h * 8;
        qf0 = *(const bf16x8*)(qp);
        qf1 = *(const bf16x8*)(qp + 16);
        qf2 = *(const bf16x8*)(qp + 32);
        qf3 = *(const bf16x8*)(qp + 48);
    }

    const u64* mp = Mb + (size_t)(b * 2048 + qb + l31) * 32 + s * 16;

    // 16B-slot swizzled fragment offsets: slot j = sub*2 + h, j' = j ^ (row&7), row=l31
    const u32 x7 = (u32)(l31 & 7);
    const u32 kof0 = (((u32)h) ^ x7) << 4;
    const u32 kof1 = (((u32)(2 + h)) ^ x7) << 4;
    const u32 kof2 = (((u32)(4 + h)) ^ x7) << 4;
    const u32 kof3 = (((u32)(6 + h)) ^ x7) << 4;
    const char* kvbase = (const char*)lK + l31 * 128;

    const u16* pK = Kb + (size_t)b * 131072 + (size_t)s * 65536 + tid * 8;
    const u16* pV = Vt + (size_t)(b * 64 + (tid >> 3)) * 2048 + s * 1024 + (tid & 7) * 8;
    const u16* pV2 = pV + 32 * 2048;

#define STAGE(BUF)                                                       \
    {                                                                    \
        gl_lds16(pK,        (char*)lK + (BUF) * 8192 + tid * 16);        \
        gl_lds16(pK + 2048, (char*)lK + (BUF) * 8192 + 4096 + tid * 16); \
        gl_lds16(pV,        (char*)lV + (BUF) * 8192 + tid * 16);        \
        gl_lds16(pV2,       (char*)lV + (BUF) * 8192 + 4096 + tid * 16); \
        pK += 4096; pV += 64; pV2 += 64;                                 \
    }

    f32x16 o0 = {}, o1 = {};
    float lsum = 0.f;
    u64 mwc;

#define FRAG(DST, IMM, OF)                                                   \
    { DST = *(const bf16x8*)(kvbase + (IMM) + (OF)); }

#define MKPA(PA, E0, E1, E2, E3, E4, E5, E6, E7)                             \
    {                                                                        \
        u32 x0_, x1_, y0_, y1_;                                              \
        asm("v_cvt_pk_bf16_f32 %0, %1, %2" : "=v"(x0_) : "v"(E0), "v"(E1));  \
        asm("v_cvt_pk_bf16_f32 %0, %1, %2" : "=v"(x1_) : "v"(E2), "v"(E3));  \
        asm("v_cvt_pk_bf16_f32 %0, %1, %2" : "=v"(y0_) : "v"(E4), "v"(E5));  \
        asm("v_cvt_pk_bf16_f32 %0, %1, %2" : "=v"(y1_) : "v"(E6), "v"(E7));  \
        asm("v_permlane32_swap_b32 %0, %1" : "+v"(x0_), "+v"(y0_));          \
        asm("v_permlane32_swap_b32 %0, %1" : "+v"(x1_), "+v"(y1_));          \
        u32x4 t_ = {x0_, x1_, y0_, y1_};                                     \
        PA = __builtin_bit_cast(bf16x8, t_);                                 \
    }

// one S^T half: C-in from LUT, 4 QK MFMAs, exp2, lsum, pack -> PA0/PA1. st dies here.
#define QKHALF(KIMM, MS, PA0, PA1)                                                      \
    {                                                                                   \
        f32x16 st;                                                                      \
        {                                                                               \
            f32x4 c0_ = slut[(u32)(MS) & 15];                                           \
            f32x4 c1_ = slut[(u32)((MS) >> 8) & 15];                                    \
            f32x4 c2_ = slut[(u32)((MS) >> 16) & 15];                                   \
            f32x4 c3_ = slut[(u32)((MS) >> 24) & 15];                                   \
            st[0] = c0_[0]; st[1] = c0_[1]; st[2] = c0_[2]; st[3] = c0_[3];             \
            st[4] = c1_[0]; st[5] = c1_[1]; st[6] = c1_[2]; st[7] = c1_[3];             \
            st[8] = c2_[0]; st[9] = c2_[1]; st[10] = c2_[2]; st[11] = c2_[3];           \
            st[12] = c3_[0]; st[13] = c3_[1]; st[14] = c3_[2]; st[15] = c3_[3];         \
        }                                                                               \
        __builtin_amdgcn_s_setprio(1);                                                  \
        {                                                                               \
            bf16x8 kf;                                                                  \
            FRAG(kf, (KIMM), kof0); st = MFMA32(kf, qf0, st);                           \
            FRAG(kf, (KIMM), kof1); st = MFMA32(kf, qf1, st);                           \
            FRAG(kf, (KIMM), kof2); st = MFMA32(kf, qf2, st);                           \
            FRAG(kf, (KIMM), kof3); st = MFMA32(kf, qf3, st);                           \
        }                                                                               \
        __builtin_amdgcn_s_setprio(0);                                                  \
        float e0 = exp2f(st[0]), e1 = exp2f(st[1]), e2 = exp2f(st[2]),                  \
              e3 = exp2f(st[3]), e4 = exp2f(st[4]), e5 = exp2f(st[5]),                  \
              e6 = exp2f(st[6]), e7 = exp2f(st[7]), e8 = exp2f(st[8]),                  \
              e9 = exp2f(st[9]), e10 = exp2f(st[10]), e11 = exp2f(st[11]),              \
              e12 = exp2f(st[12]), e13 = exp2f(st[13]), e14 = exp2f(st[14]),            \
              e15 = exp2f(st[15]);                                                      \
        lsum += (((e0 + e1) + (e2 + e3)) + ((e4 + e5) + (e6 + e7))) +                   \
                (((e8 + e9) + (e10 + e11)) + ((e12 + e13) + (e14 + e15)));              \
        MKPA(PA0, e0, e1, e2, e3, e4, e5, e6, e7);                                      \
        MKPA(PA1, e8, e9, e10, e11, e12, e13, e14, e15);                                \
    }

// PV for one k-half: pa0 = k-slice (slot OFA), pa1 = k-slice (slot OFB).
#define PVHALF(VIMM, OFA, OFB)                                                          \
    {                                                                                   \
        __builtin_amdgcn_s_setprio(1);                                                  \
        bf16x8 vv;                                                                      \
        FRAG(vv, (VIMM),        OFA); o0 = MFMA32(pa0, vv, o0);                         \
        FRAG(vv, (VIMM) + 4096, OFA); o1 = MFMA32(pa0, vv, o1);                         \
        FRAG(vv, (VIMM),        OFB); o0 = MFMA32(pa1, vv, o0);                         \
        FRAG(vv, (VIMM) + 4096, OFB); o1 = MFMA32(pa1, vv, o1);                         \
        __builtin_amdgcn_s_setprio(0);                                                  \
    }

#define CHUNK(BUF, KCL, LAST)                                                           \
    {                                                                                   \
        if (!(LAST)) STAGE((BUF) ^ 1);                                                  \
        u64 ms_ = mwc >> (4 * h);                                                       \
        mwc = mp[(KCL) + 1];                                                            \
        bf16x8 pa0, pa1;                                                                \
        QKHALF((BUF) * 8192,        (u32)ms_,         pa0, pa1);                        \
        PVHALF(16384 + (BUF) * 8192, kof0, kof1);                                       \
        QKHALF((BUF) * 8192 + 4096, (u32)(ms_ >> 32), pa0, pa1);                        \
        PVHALF(16384 + (BUF) * 8192, kof2, kof3);                                       \
        __syncthreads();                                                                \
    }

    STAGE(0);
    mwc = mp[0];
    __syncthreads();

    for (int t2 = 0; t2 < 8; ++t2) {
        CHUNK(0, 2 * t2, false);
        CHUNK(1, 2 * t2 + 1, t2 == 7);
    }
#undef STAGE
#undef CHUNK
#undef QKHALF
#undef PVHALF
#undef FRAG
#undef MKPA

    lsum += __shfl_xor(lsum, 32);
    u16* op = (s ? oPb : oPa) + (size_t)(b * 2048 + qb) * 1024 + hh * 64 + l31;
    if (h == 0) {
        float* lp = (s ? lsPb : lsPa);
        lp[(b * 16 + hh) * 2048 + qb + l31] = lsum;
    }
#pragma unroll
    for (int r = 0; r < 16; ++r) {
        int qloc = (r & 3) + 8 * (r >> 2) + 4 * h;
        op[(size_t)qloc * 1024]      = f2bf(o0[r]);
        op[(size_t)qloc * 1024 + 32] = f2bf(o1[r]);
    }
}

// ---------------- launch ----------------
extern "C" void kernel_launch(void* const* d_in, const int* in_sizes, int n_in,
                              void* d_out, int out_size, void* d_ws, size_t ws_size,
                              hipStream_t stream) {
    (void)in_sizes; (void)n_in; (void)out_size; (void)ws_size;
    const float* inq  = (const float*)d_in[0];
    const float* inkv = (const float*)d_in[1];
    const void*  mask = d_in[2];
    const float* Wq   = (const float*)d_in[3];
    const float* bq   = (const float*)d_in[4];
    const float* Wk   = (const float*)d_in[5];
    const float* bk   = (const float*)d_in[6];
    const float* Wv   = (const float*)d_in[7];
    const float* bv   = (const float*)d_in[8];
    const float* Wo   = (const float*)d_in[9];
    const float* bo   = (const float*)d_in[10];
    float* out = (float*)d_out;

    char* ws = (char*)d_ws;
    f32x4* lut   = (f32x4*)(ws + 256);           // 256 B (16 x f32x4)
    u16* Aq   = (u16*)(ws + 512);                // 4096x1024 (dead after gemm0 -> oPa)
    u16* Akv  = Aq + 4194304;                    // 4096x1024 (dead after gemm0 -> oPb)
    u16* Wcat = Akv + 4194304;                   // 1152x1024 (dead after gemm0 -> lsP)
    u16* Wot  = Wcat + 1179648;                  // 1024x1024
    u16* Qb   = Wot + 1048576;                   // 4096x1024 (roped, *QSCALE)
    u16* Kbf  = Qb + 4194304;                    // 4096x64 swizzled (+ pad)
    u16* Vtb  = Kbf + 266496;                    // 2x64x2048 swizzled (+ pad)
    u16* Ob   = Vtb + 266496;                    // (unused; kept for layout)
    u64* Mb   = (u64*)(Ob + 4194304);            // 131072 words (+8 pad)
    float2* rtbl = (float2*)(Mb + 131080);       // 2048x32 cos/sin

    u16* oPa = Aq;
    u16* oPb = Akv;
    float* lsPa = (float*)Wcat;                  // 65536 f32
    float* lsPb = lsPa + 65536;                  // 65536 f32

    prep<<<12672, 256, 0, stream>>>((const float4*)inq, (const float4*)inkv,
                                    (ushort4*)Aq, (ushort4*)Akv,
                                    Wq, Wk, Wv, Wo, Wcat, Wot,
                                    mask, Mb, rtbl, (float*)lut);
    gemm_bt<0><<<576, 256, 0, stream>>>(Aq, Akv, Wcat, bq, bk, bv, rtbl,
                                        Qb, Kbf, Vtb, nullptr, 9);
    flash<<<1024, 256, 0, stream>>>(Qb, Kbf, Vtb, Mb, lut, oPa, oPb, lsPa, lsPb);
    gemm_bt<2><<<512, 256, 0, stream>>>(oPa, oPb, Wot, bo, lsPa, lsPb, rtbl,
                                        nullptr, nullptr, nullptr, out, 8);
}